// Round 2
// baseline (1173.681 us; speedup 1.0000x reference)
//
#include <hip/hip_runtime.h>
#include <math.h>

#define N 1536
#define E 24576
#define HD 128
#define D 1280
#define NW 24   // 1536/64 bitmask words per row

typedef unsigned long long u64;
typedef unsigned short u16;

__device__ __forceinline__ double lrelu(double v){ return v > 0.0 ? v : 0.2*v; }

// ---- IN bitmask (in-neighbors from the E raw edges) + in-degree incl. self-loop
__global__ void k_deg_in(const int* __restrict__ ei, u64* __restrict__ IN, int* __restrict__ deg){
    int idx = blockIdx.x*blockDim.x + threadIdx.x;
    if (idx < E){
        int s = ei[idx], t = ei[E+idx];
        atomicOr(&IN[(size_t)t*NW + (s>>6)], 1ULL << (s&63));
        atomicAdd(&deg[t], 1);
    } else if (idx < E+N){
        atomicAdd(&deg[idx-E], 1);
    }
}

// ---- exclusive scan of deg (1536 entries) -> coff[0..N], cursor copy
__global__ void k_scan(const int* __restrict__ deg, int* __restrict__ coff, int* __restrict__ cursor){
    __shared__ int ls[256];
    int tid = threadIdx.x;
    int v[6]; int s = 0;
    for (int u=0; u<6; u++){ v[u] = s; s += deg[tid*6+u]; }
    ls[tid] = s; __syncthreads();
    for (int d=1; d<256; d<<=1){
        int t2 = (tid>=d) ? ls[tid-d] : 0;
        __syncthreads();
        ls[tid] += t2;
        __syncthreads();
    }
    int base = (tid>0) ? ls[tid-1] : 0;
    for (int u=0; u<6; u++){
        int o = base + v[u];
        coff[tid*6+u] = o; cursor[tid*6+u] = o;
    }
    if (tid==255) coff[N] = ls[255];
}

// ---- fill CSR of in-edge sources (duplicates preserved; self-loops appended)
__global__ void k_fill(const int* __restrict__ ei, int* __restrict__ cursor, int* __restrict__ csr_src){
    int idx = blockIdx.x*blockDim.x + threadIdx.x;
    if (idx < E){
        int s = ei[idx], t = ei[E+idx];
        int p = atomicAdd(&cursor[t], 1);
        csr_src[p] = s;
    } else if (idx < E+N){
        int t = idx - E;
        int p = atomicAdd(&cursor[t], 1);
        csr_src[p] = t;
    }
}

// ---- 2-hop reachability row + column list. One wave per row.
__global__ void k_mrow(const u64* __restrict__ IN, u64* __restrict__ Mb,
                       u16* __restrict__ cols, int* __restrict__ cnt){
    int i = blockIdx.x, ln = threadIdx.x;   // blockDim = 64
    __shared__ u64 m1[NW];
    __shared__ int scn[64];
    u64 R = 0;
    if (ln < NW){
        u64 b = IN[(size_t)i*NW + ln];
        if ((i>>6) == ln) b |= 1ULL << (i&63);
        m1[ln] = b; R = b;
    }
    __syncthreads();
    for (int w=0; w<NW; w++){
        u64 bits = m1[w];                    // uniform across lanes
        while (bits){
            int k = __ffsll((unsigned long long)bits) - 1;
            bits &= bits - 1;
            int node = w*64 + k;
            if (ln < NW) R |= IN[(size_t)node*NW + ln];
        }
    }
    if (ln < NW) Mb[(size_t)i*NW + ln] = R;
    int pc = (ln < NW) ? __popcll(R) : 0;
    scn[ln] = pc; __syncthreads();
    for (int d=1; d<64; d<<=1){
        int v = (ln>=d) ? scn[ln-d] : 0;
        __syncthreads();
        scn[ln] += v;
        __syncthreads();
    }
    if (ln == 63) cnt[i] = scn[63];
    int idx = scn[ln] - pc;
    u64 bb = R;
    while (bb){
        int b = __ffsll((unsigned long long)bb) - 1;
        bb &= bb - 1;
        cols[(size_t)i*N + idx++] = (u16)(ln*64 + b);
    }
}

// ---- h = x @ W1 (f64). grid (D/256, N). Two acc chains + unroll for MLP.
__global__ void k_h(const float* __restrict__ x, const float* __restrict__ W1, double* __restrict__ h64){
    int i = blockIdx.y, tid = threadIdx.x;
    int col = blockIdx.x*256 + tid;
    __shared__ double xL[HD];
    if (tid < HD) xL[tid] = (double)x[(size_t)i*HD + tid];
    __syncthreads();
    double a0 = 0.0, a1 = 0.0;
    const float* wp = &W1[col];
    #pragma unroll
    for (int k=0; k<HD; k+=2){
        a0 += xL[k]   * (double)wp[(size_t)k*D];
        a1 += xL[k+1] * (double)wp[(size_t)(k+1)*D];
    }
    h64[(size_t)i*D + col] = a0 + a1;
}

// ---- hs1 = h@a_src1, hd1 = h@a_dst1
__global__ void k_hv(const double* __restrict__ h64, const float* __restrict__ as1,
                     const float* __restrict__ ad1, double* __restrict__ hs1, double* __restrict__ hd1){
    int i = blockIdx.x, tid = threadIdx.x;
    __shared__ double ra[256], rb[256];
    double a = 0, b = 0;
    for (int d=tid; d<D; d+=256){
        double hv = h64[(size_t)i*D + d];
        a += hv * (double)as1[d];
        b += hv * (double)ad1[d];
    }
    ra[tid] = a; rb[tid] = b; __syncthreads();
    for (int s=128; s>0; s>>=1){
        if (tid < s){ ra[tid] += ra[tid+s]; rb[tid] += rb[tid+s]; }
        __syncthreads();
    }
    if (tid == 0){ hs1[i] = ra[0]; hd1[i] = rb[0]; }
}

// ---- stage-1 GAT gather per target: softmax over in-edges, g = (x_gat+b1)*w2
__global__ void k_gat(const int* __restrict__ coff, const int* __restrict__ csr_src,
                      const double* __restrict__ hs1, const double* __restrict__ hd1,
                      const double* __restrict__ h64,
                      const float* __restrict__ b1, const float* __restrict__ w2,
                      double* __restrict__ g64){
    int t = blockIdx.x, tid = threadIdx.x;
    int o0 = coff[t], o1 = coff[t+1], dg = o1 - o0;
    __shared__ double ms[256], ds[256], als[256];
    __shared__ int ssrc[256];
    __shared__ double MM, DD;
    double hdt = hd1[t];
    double m = -INFINITY, dsum = 0.0;
    for (int j=tid; j<dg; j+=256){
        int s = csr_src[o0+j];
        double e = lrelu(hs1[s] + hdt);
        if (e > m){ dsum = dsum*exp(m-e) + 1.0; m = e; }
        else dsum += exp(e-m);
    }
    ms[tid] = m; ds[tid] = dsum; __syncthreads();
    for (int step=128; step>0; step>>=1){
        if (tid < step){
            double m1 = ms[tid], d1 = ds[tid];
            double m2 = ms[tid+step], d2 = ds[tid+step];
            double M = fmax(m1, m2), Dv = 0.0;
            if (d1 > 0.0) Dv += d1*exp(m1-M);
            if (d2 > 0.0) Dv += d2*exp(m2-M);
            ms[tid] = M; ds[tid] = Dv;
        }
        __syncthreads();
    }
    if (tid == 0){ MM = ms[0]; DD = ds[0]; }
    __syncthreads();
    double M = MM, Dv = DD;
    double acc[5] = {0,0,0,0,0};
    for (int base=0; base<dg; base+=256){
        int j = base + tid;
        if (j < dg){
            int s = csr_src[o0+j];
            double e = lrelu(hs1[s] + hdt);
            als[tid] = exp(e-M)/Dv; ssrc[tid] = s;
        }
        __syncthreads();
        int lim = min(256, dg-base);
        for (int u=0; u<lim; u++){
            double a = als[u];
            const double* hp = &h64[(size_t)ssrc[u]*D];
            #pragma unroll
            for (int q=0; q<5; q++) acc[q] += a * hp[tid + 256*q];
        }
        __syncthreads();
    }
    #pragma unroll
    for (int q=0; q<5; q++){
        int d = tid + 256*q;
        g64[(size_t)t*D + d] = (acc[q] + (double)b1[d]) * (double)w2[d];
    }
}

// ---- sparse H2 row: H2[i,j] = g[i]·x_orig[j] only for j in Mb[i].
// One wave handles 8 columns concurrently; g-row held in registers (20 dbl/lane);
// fully unrolled -> ~160 independent loads in flight per wave.
__global__ void k_h2(const double* __restrict__ g64, const float* __restrict__ xo,
                     const u16* __restrict__ cols, const int* __restrict__ cnt,
                     double* __restrict__ H2){
    int i = blockIdx.x, tid = threadIdx.x;
    int wv = tid >> 6, ln = tid & 63;
    double gr[20];
    #pragma unroll
    for (int k=0; k<20; k++) gr[k] = g64[(size_t)i*D + ln + 64*k];
    int c0 = cnt[i];
    const u16* cp = &cols[(size_t)i*N];
    for (int cb = wv*8; cb < c0; cb += 32){
        int nv = min(8, c0 - cb);
        const float* p[8];
        int jj[8];
        #pragma unroll
        for (int q=0; q<8; q++){
            int cc = cb + (q < nv ? q : 0);
            jj[q] = cp[cc];
            p[q] = &xo[(size_t)jj[q]*D + ln];
        }
        double ac[8] = {0,0,0,0,0,0,0,0};
        #pragma unroll
        for (int k=0; k<20; k++){
            double gv = gr[k];
            #pragma unroll
            for (int q=0; q<8; q++) ac[q] += gv * (double)p[q][64*k];
        }
        #pragma unroll
        for (int q=0; q<8; q++){
            double a = ac[q];
            #pragma unroll
            for (int o=32; o>0; o>>=1) a += __shfl_down(a, o, 64);
            if (ln == 0 && q < nv) H2[(size_t)i*N + jj[q]] = a;
        }
    }
}

// ---- stage-2 masked segment softmax score, gather per (row, target in Mb[i])
__global__ void k_score(const double* __restrict__ H2, const u64* __restrict__ Mb,
                        const u16* __restrict__ cols, const int* __restrict__ cnt,
                        const int* __restrict__ coff, const int* __restrict__ csr_src,
                        const float* __restrict__ pas2, const float* __restrict__ pad2,
                        const float* __restrict__ pb2, double* __restrict__ score){
    int i = blockIdx.x, tid = threadIdx.x;
    __shared__ double HL[N];
    __shared__ u64 MbL[NW];
    for (int d=tid; d<N; d+=256) HL[d] = H2[(size_t)i*N + d];
    if (tid < NW) MbL[tid] = Mb[(size_t)i*NW + tid];
    __syncthreads();
    double as2 = (double)pas2[0], ad2 = (double)pad2[0], b2 = (double)pb2[0];
    int c0 = cnt[i];
    for (int c=tid; c<c0; c+=256){
        int t = cols[(size_t)i*N + c];
        double ht = HL[t];
        int o0 = coff[t], o1 = coff[t+1];
        double m = -INFINITY, den = 0.0, nu = 0.0;
        for (int p=o0; p<o1; p++){
            int s = csr_src[p];
            if ((MbL[s>>6] >> (s&63)) & 1ULL){
                double hs = HL[s];
                double z = as2*hs + ad2*ht;
                double e = z > 0.0 ? z : 0.2*z;
                if (e > m){
                    double sc = exp(m-e);     // exp(-inf)=0 on first valid edge
                    den = den*sc + 1.0;
                    nu  = nu*sc + hs;
                    m = e;
                } else {
                    double w = exp(e-m);
                    den += w; nu += w*hs;
                }
            }
        }
        score[(size_t)i*N + t] = nu / fmax(den, 1e-12) + b2;
    }
}

// ---- per-row top-k selection (stable index tie-break) + outputs
__global__ void k_rank(const double* __restrict__ score, const u16* __restrict__ cols,
                       const int* __restrict__ cnt, float* __restrict__ out){
    int i = blockIdx.x, tid = threadIdx.x;
    __shared__ double scL[N];
    __shared__ u16 clL[N];
    int c0 = cnt[i];
    for (int c=tid; c<c0; c+=256){
        int t = cols[(size_t)i*N + c];
        clL[c] = (u16)t;
        scL[c] = score[(size_t)i*N + t];
    }
    __syncthreads();
    int k = (c0 + 1) >> 1;                 // ceil(0.5*size)
    float* keepO = out + (size_t)N*N;
    for (int p=tid; p<c0; p+=256){
        double s = scL[p]; int col = clL[p];
        int r = 0;
        for (int q=0; q<c0; q++){
            double sq = scL[q];
            r += (sq > s) || (sq == s && clL[q] < col);
        }
        if (r < k){
            out[(size_t)i*N + col]   = (float)(1.0/(1.0 + exp(-s)));
            keepO[(size_t)i*N + col] = 1.0f;
        }
    }
}

extern "C" void kernel_launch(void* const* d_in, const int* in_sizes, int n_in,
                              void* d_out, int out_size, void* d_ws, size_t ws_size,
                              hipStream_t stream){
    const float* x   = (const float*)d_in[0];
    const float* xo  = (const float*)d_in[1];
    const int*   ei  = (const int*)  d_in[2];
    // d_in[3] = batch (unused)
    const float* W1  = (const float*)d_in[4];
    const float* as1 = (const float*)d_in[5];
    const float* ad1 = (const float*)d_in[6];
    const float* b1  = (const float*)d_in[7];
    const float* w2  = (const float*)d_in[8];
    const float* as2 = (const float*)d_in[9];
    const float* ad2 = (const float*)d_in[10];
    const float* b2  = (const float*)d_in[11];
    float* out = (float*)d_out;

    char* w = (char*)d_ws;
    size_t o = 0;
    auto alloc = [&](size_t b)->char*{ char* r = w + o; o = (o + b + 255) & ~(size_t)255; return r; };

    double* h64   = (double*)alloc((size_t)N*D*8);   // dead after k_gat
    double* g64   = (double*)alloc((size_t)N*D*8);   // dead after k_h2
    double* H2    = (double*)alloc((size_t)N*N*8);
    u64*    IN    = (u64*)   alloc((size_t)N*NW*8);
    u64*    Mb    = (u64*)   alloc((size_t)N*NW*8);
    double* hs1   = (double*)alloc((size_t)N*8);
    double* hd1   = (double*)alloc((size_t)N*8);
    int*    deg   = (int*)   alloc((size_t)N*4);
    int*    coff  = (int*)   alloc((size_t)(N+1)*4);
    int*    cursor= (int*)   alloc((size_t)N*4);
    int*    csr   = (int*)   alloc((size_t)(E+N)*4);
    u16*    cols  = (u16*)   alloc((size_t)N*N*2);
    int*    cnt   = (int*)   alloc((size_t)N*4);
    // score overlays h64+g64 (both dead by the time k_score runs): 18.9MB <= 31.4MB
    double* score = (double*)h64;

    hipMemsetAsync(IN,  0, (size_t)N*NW*8, stream);
    hipMemsetAsync(deg, 0, (size_t)N*4,    stream);
    hipMemsetAsync(d_out, 0, (size_t)out_size*sizeof(float), stream);

    k_deg_in<<<(E+N+255)/256, 256, 0, stream>>>(ei, IN, deg);
    k_scan  <<<1, 256, 0, stream>>>(deg, coff, cursor);
    k_fill  <<<(E+N+255)/256, 256, 0, stream>>>(ei, cursor, csr);
    k_mrow  <<<N, 64, 0, stream>>>(IN, Mb, cols, cnt);
    k_h     <<<dim3(D/256, N), 256, 0, stream>>>(x, W1, h64);
    k_hv    <<<N, 256, 0, stream>>>(h64, as1, ad1, hs1, hd1);
    k_gat   <<<N, 256, 0, stream>>>(coff, csr, hs1, hd1, h64, b1, w2, g64);
    k_h2    <<<N, 256, 0, stream>>>(g64, xo, cols, cnt, H2);
    k_score <<<N, 256, 0, stream>>>(H2, Mb, cols, cnt, coff, csr, as2, ad2, b2, score);
    k_rank  <<<N, 256, 0, stream>>>(score, cols, cnt, out);
}

// Round 3
// 416.258 us; speedup vs baseline: 2.8196x; 2.8196x over previous
//
#include <hip/hip_runtime.h>
#include <math.h>

#define N 1536
#define E 24576
#define HD 128
#define D 1280
#define NW 24   // 1536/64 bitmask words per row
#define RT 16   // rows per block in k_h

typedef unsigned long long u64;
typedef unsigned short u16;

__device__ __forceinline__ double lrelu(double v){ return v > 0.0 ? v : 0.2*v; }

// ---- IN bitmask (in-neighbors from the E raw edges) + in-degree incl. self-loop
__global__ void k_deg_in(const int* __restrict__ ei, u64* __restrict__ IN, int* __restrict__ deg){
    int idx = blockIdx.x*blockDim.x + threadIdx.x;
    if (idx < E){
        int s = ei[idx], t = ei[E+idx];
        atomicOr(&IN[(size_t)t*NW + (s>>6)], 1ULL << (s&63));
        atomicAdd(&deg[t], 1);
    } else if (idx < E+N){
        atomicAdd(&deg[idx-E], 1);
    }
}

// ---- exclusive scan of deg (1536 entries) -> coff[0..N], cursor copy
__global__ void k_scan(const int* __restrict__ deg, int* __restrict__ coff, int* __restrict__ cursor){
    __shared__ int ls[256];
    int tid = threadIdx.x;
    int v[6]; int s = 0;
    for (int u=0; u<6; u++){ v[u] = s; s += deg[tid*6+u]; }
    ls[tid] = s; __syncthreads();
    for (int d=1; d<256; d<<=1){
        int t2 = (tid>=d) ? ls[tid-d] : 0;
        __syncthreads();
        ls[tid] += t2;
        __syncthreads();
    }
    int base = (tid>0) ? ls[tid-1] : 0;
    for (int u=0; u<6; u++){
        int o = base + v[u];
        coff[tid*6+u] = o; cursor[tid*6+u] = o;
    }
    if (tid==255) coff[N] = ls[255];
}

// ---- fill CSR of in-edge sources (duplicates preserved; self-loops appended)
__global__ void k_fill(const int* __restrict__ ei, int* __restrict__ cursor, int* __restrict__ csr_src){
    int idx = blockIdx.x*blockDim.x + threadIdx.x;
    if (idx < E){
        int s = ei[idx], t = ei[E+idx];
        int p = atomicAdd(&cursor[t], 1);
        csr_src[p] = s;
    } else if (idx < E+N){
        int t = idx - E;
        int p = atomicAdd(&cursor[t], 1);
        csr_src[p] = t;
    }
}

// ---- 2-hop reachability row + column list. One wave per row.
__global__ void k_mrow(const u64* __restrict__ IN, u64* __restrict__ Mb,
                       u16* __restrict__ cols, int* __restrict__ cnt){
    int i = blockIdx.x, ln = threadIdx.x;   // blockDim = 64
    __shared__ u64 m1[NW];
    __shared__ int scn[64];
    u64 R = 0;
    if (ln < NW){
        u64 b = IN[(size_t)i*NW + ln];
        if ((i>>6) == ln) b |= 1ULL << (i&63);
        m1[ln] = b; R = b;
    }
    __syncthreads();
    for (int w=0; w<NW; w++){
        u64 bits = m1[w];                    // uniform across lanes
        while (bits){
            int k = __ffsll((unsigned long long)bits) - 1;
            bits &= bits - 1;
            int node = w*64 + k;
            if (ln < NW) R |= IN[(size_t)node*NW + ln];
        }
    }
    if (ln < NW) Mb[(size_t)i*NW + ln] = R;
    int pc = (ln < NW) ? __popcll(R) : 0;
    scn[ln] = pc; __syncthreads();
    for (int d=1; d<64; d<<=1){
        int v = (ln>=d) ? scn[ln-d] : 0;
        __syncthreads();
        scn[ln] += v;
        __syncthreads();
    }
    if (ln == 63) cnt[i] = scn[63];
    int idx = scn[ln] - pc;
    u64 bb = R;
    while (bb){
        int b = __ffsll((unsigned long long)bb) - 1;
        bb &= bb - 1;
        cols[(size_t)i*N + idx++] = (u16)(ln*64 + b);
    }
}

// ---- h = x @ W1 (f64). grid (D/256, N/RT). 16 rows/block: W1 reuse + 16 indep chains.
__global__ void k_h(const float* __restrict__ x, const float* __restrict__ W1, double* __restrict__ h64){
    int rb = blockIdx.y*RT, tid = threadIdx.x;
    int col = blockIdx.x*256 + tid;
    __shared__ double xL[RT*HD];   // 16 KB
    for (int u=tid; u<RT*HD; u+=256) xL[u] = (double)x[(size_t)rb*HD + u];
    __syncthreads();
    double acc[RT];
    #pragma unroll
    for (int r=0; r<RT; r++) acc[r] = 0.0;
    const float* wp = &W1[col];
    #pragma unroll 4
    for (int k=0; k<HD; k++){
        double w = (double)wp[(size_t)k*D];
        #pragma unroll
        for (int r=0; r<RT; r++) acc[r] += w * xL[r*HD + k];  // LDS broadcast
    }
    #pragma unroll
    for (int r=0; r<RT; r++) h64[(size_t)(rb+r)*D + col] = acc[r];
}

// ---- hs1 = h@a_src1, hd1 = h@a_dst1
__global__ void k_hv(const double* __restrict__ h64, const float* __restrict__ as1,
                     const float* __restrict__ ad1, double* __restrict__ hs1, double* __restrict__ hd1){
    int i = blockIdx.x, tid = threadIdx.x;
    __shared__ double ra[256], rb[256];
    double a = 0, b = 0;
    for (int d=tid; d<D; d+=256){
        double hv = h64[(size_t)i*D + d];
        a += hv * (double)as1[d];
        b += hv * (double)ad1[d];
    }
    ra[tid] = a; rb[tid] = b; __syncthreads();
    for (int s=128; s>0; s>>=1){
        if (tid < s){ ra[tid] += ra[tid+s]; rb[tid] += rb[tid+s]; }
        __syncthreads();
    }
    if (tid == 0){ hs1[i] = ra[0]; hd1[i] = rb[0]; }
}

// ---- stage-1 GAT gather per target: softmax over in-edges, g = (x_gat+b1)*w2
__global__ void k_gat(const int* __restrict__ coff, const int* __restrict__ csr_src,
                      const double* __restrict__ hs1, const double* __restrict__ hd1,
                      const double* __restrict__ h64,
                      const float* __restrict__ b1, const float* __restrict__ w2,
                      double* __restrict__ g64){
    int t = blockIdx.x, tid = threadIdx.x;
    int o0 = coff[t], o1 = coff[t+1], dg = o1 - o0;
    __shared__ double ms[256], ds[256], als[256];
    __shared__ int ssrc[256];
    __shared__ double MM, DD;
    double hdt = hd1[t];
    double m = -INFINITY, dsum = 0.0;
    for (int j=tid; j<dg; j+=256){
        int s = csr_src[o0+j];
        double e = lrelu(hs1[s] + hdt);
        if (e > m){ dsum = dsum*exp(m-e) + 1.0; m = e; }
        else dsum += exp(e-m);
    }
    ms[tid] = m; ds[tid] = dsum; __syncthreads();
    for (int step=128; step>0; step>>=1){
        if (tid < step){
            double m1 = ms[tid], d1 = ds[tid];
            double m2 = ms[tid+step], d2 = ds[tid+step];
            double M = fmax(m1, m2), Dv = 0.0;
            if (d1 > 0.0) Dv += d1*exp(m1-M);
            if (d2 > 0.0) Dv += d2*exp(m2-M);
            ms[tid] = M; ds[tid] = Dv;
        }
        __syncthreads();
    }
    if (tid == 0){ MM = ms[0]; DD = ds[0]; }
    __syncthreads();
    double M = MM, Dv = DD;
    double acc[5] = {0,0,0,0,0};
    for (int base=0; base<dg; base+=256){
        int j = base + tid;
        if (j < dg){
            int s = csr_src[o0+j];
            double e = lrelu(hs1[s] + hdt);
            als[tid] = exp(e-M)/Dv; ssrc[tid] = s;
        }
        __syncthreads();
        int lim = min(256, dg-base);
        for (int u=0; u<lim; u++){
            double a = als[u];
            const double* hp = &h64[(size_t)ssrc[u]*D];
            #pragma unroll
            for (int q=0; q<5; q++) acc[q] += a * hp[tid + 256*q];
        }
        __syncthreads();
    }
    #pragma unroll
    for (int q=0; q<5; q++){
        int d = tid + 256*q;
        g64[(size_t)t*D + d] = (acc[q] + (double)b1[d]) * (double)w2[d];
    }
}

// ---- sparse H2 row: H2[i,j] = g[i]·x_orig[j] only for j in Mb[i].
// v3: g fragment in registers in float4-matched layout (constant-indexed, no spill);
// 2 columns/wave -> 10 dwordx4 loads in flight; no LDS, no pointer arrays.
__global__ __launch_bounds__(256, 4)
void k_h2(const double* __restrict__ g64, const float* __restrict__ xo,
          const u16* __restrict__ cols, const int* __restrict__ cnt,
          double* __restrict__ H2){
    int i = blockIdx.x, tid = threadIdx.x;
    int wv = tid >> 6, ln = tid & 63;
    double gr[5][4];
    #pragma unroll
    for (int k=0; k<5; k++){
        #pragma unroll
        for (int c=0; c<4; c++) gr[k][c] = g64[(size_t)i*D + ln*4 + 256*k + c];
    }
    int c0 = cnt[i];
    const u16* cp = &cols[(size_t)i*N];
    for (int cb = wv*2; cb < c0; cb += 8){
        int j0 = cp[cb];
        int j1 = cp[(cb+1 < c0) ? cb+1 : cb];
        const float4* p0 = (const float4*)(&xo[(size_t)j0*D]) + ln;
        const float4* p1 = (const float4*)(&xo[(size_t)j1*D]) + ln;
        double a0 = 0.0, a1 = 0.0;
        #pragma unroll
        for (int k=0; k<5; k++){
            float4 v0 = p0[64*k];
            float4 v1 = p1[64*k];
            a0 += gr[k][0]*(double)v0.x + gr[k][1]*(double)v0.y
                + gr[k][2]*(double)v0.z + gr[k][3]*(double)v0.w;
            a1 += gr[k][0]*(double)v1.x + gr[k][1]*(double)v1.y
                + gr[k][2]*(double)v1.z + gr[k][3]*(double)v1.w;
        }
        #pragma unroll
        for (int o=32; o>0; o>>=1){
            a0 += __shfl_down(a0, o, 64);
            a1 += __shfl_down(a1, o, 64);
        }
        if (ln == 0){
            H2[(size_t)i*N + j0] = a0;
            if (cb+1 < c0) H2[(size_t)i*N + j1] = a1;
        }
    }
}

// ---- stage-2 masked segment softmax score, gather per (row, target in Mb[i])
__global__ void k_score(const double* __restrict__ H2, const u64* __restrict__ Mb,
                        const u16* __restrict__ cols, const int* __restrict__ cnt,
                        const int* __restrict__ coff, const int* __restrict__ csr_src,
                        const float* __restrict__ pas2, const float* __restrict__ pad2,
                        const float* __restrict__ pb2, double* __restrict__ score){
    int i = blockIdx.x, tid = threadIdx.x;
    __shared__ double HL[N];
    __shared__ u64 MbL[NW];
    for (int d=tid; d<N; d+=256) HL[d] = H2[(size_t)i*N + d];
    if (tid < NW) MbL[tid] = Mb[(size_t)i*NW + tid];
    __syncthreads();
    double as2 = (double)pas2[0], ad2 = (double)pad2[0], b2 = (double)pb2[0];
    int c0 = cnt[i];
    for (int c=tid; c<c0; c+=256){
        int t = cols[(size_t)i*N + c];
        double ht = HL[t];
        int o0 = coff[t], o1 = coff[t+1];
        double m = -INFINITY, den = 0.0, nu = 0.0;
        for (int p=o0; p<o1; p++){
            int s = csr_src[p];
            if ((MbL[s>>6] >> (s&63)) & 1ULL){
                double hs = HL[s];
                double z = as2*hs + ad2*ht;
                double e = z > 0.0 ? z : 0.2*z;
                if (e > m){
                    double sc = exp(m-e);     // exp(-inf)=0 on first valid edge
                    den = den*sc + 1.0;
                    nu  = nu*sc + hs;
                    m = e;
                } else {
                    double w = exp(e-m);
                    den += w; nu += w*hs;
                }
            }
        }
        score[(size_t)i*N + t] = nu / fmax(den, 1e-12) + b2;
    }
}

// ---- per-row top-k selection (stable index tie-break) + outputs
__global__ void k_rank(const double* __restrict__ score, const u16* __restrict__ cols,
                       const int* __restrict__ cnt, float* __restrict__ out){
    int i = blockIdx.x, tid = threadIdx.x;
    __shared__ double scL[N];
    __shared__ u16 clL[N];
    int c0 = cnt[i];
    for (int c=tid; c<c0; c+=256){
        int t = cols[(size_t)i*N + c];
        clL[c] = (u16)t;
        scL[c] = score[(size_t)i*N + t];
    }
    __syncthreads();
    int k = (c0 + 1) >> 1;                 // ceil(0.5*size)
    float* keepO = out + (size_t)N*N;
    for (int p=tid; p<c0; p+=256){
        double s = scL[p]; int col = clL[p];
        int r = 0;
        for (int q=0; q<c0; q++){
            double sq = scL[q];
            r += (sq > s) || (sq == s && clL[q] < col);
        }
        if (r < k){
            out[(size_t)i*N + col]   = (float)(1.0/(1.0 + exp(-s)));
            keepO[(size_t)i*N + col] = 1.0f;
        }
    }
}

extern "C" void kernel_launch(void* const* d_in, const int* in_sizes, int n_in,
                              void* d_out, int out_size, void* d_ws, size_t ws_size,
                              hipStream_t stream){
    const float* x   = (const float*)d_in[0];
    const float* xo  = (const float*)d_in[1];
    const int*   ei  = (const int*)  d_in[2];
    // d_in[3] = batch (unused)
    const float* W1  = (const float*)d_in[4];
    const float* as1 = (const float*)d_in[5];
    const float* ad1 = (const float*)d_in[6];
    const float* b1  = (const float*)d_in[7];
    const float* w2  = (const float*)d_in[8];
    const float* as2 = (const float*)d_in[9];
    const float* ad2 = (const float*)d_in[10];
    const float* b2  = (const float*)d_in[11];
    float* out = (float*)d_out;

    char* w = (char*)d_ws;
    size_t o = 0;
    auto alloc = [&](size_t b)->char*{ char* r = w + o; o = (o + b + 255) & ~(size_t)255; return r; };

    double* h64   = (double*)alloc((size_t)N*D*8);   // dead after k_gat
    double* g64   = (double*)alloc((size_t)N*D*8);   // dead after k_h2
    double* H2    = (double*)alloc((size_t)N*N*8);
    u64*    IN    = (u64*)   alloc((size_t)N*NW*8);
    u64*    Mb    = (u64*)   alloc((size_t)N*NW*8);
    double* hs1   = (double*)alloc((size_t)N*8);
    double* hd1   = (double*)alloc((size_t)N*8);
    int*    deg   = (int*)   alloc((size_t)N*4);
    int*    coff  = (int*)   alloc((size_t)(N+1)*4);
    int*    cursor= (int*)   alloc((size_t)N*4);
    int*    csr   = (int*)   alloc((size_t)(E+N)*4);
    u16*    cols  = (u16*)   alloc((size_t)N*N*2);
    int*    cnt   = (int*)   alloc((size_t)N*4);
    // score overlays h64+g64 (both dead by the time k_score runs): 18.9MB <= 31.4MB
    double* score = (double*)h64;

    hipMemsetAsync(IN,  0, (size_t)N*NW*8, stream);
    hipMemsetAsync(deg, 0, (size_t)N*4,    stream);
    hipMemsetAsync(d_out, 0, (size_t)out_size*sizeof(float), stream);

    k_deg_in<<<(E+N+255)/256, 256, 0, stream>>>(ei, IN, deg);
    k_scan  <<<1, 256, 0, stream>>>(deg, coff, cursor);
    k_fill  <<<(E+N+255)/256, 256, 0, stream>>>(ei, cursor, csr);
    k_mrow  <<<N, 64, 0, stream>>>(IN, Mb, cols, cnt);
    k_h     <<<dim3(D/256, N/RT), 256, 0, stream>>>(x, W1, h64);
    k_hv    <<<N, 256, 0, stream>>>(h64, as1, ad1, hs1, hd1);
    k_gat   <<<N, 256, 0, stream>>>(coff, csr, hs1, hd1, h64, b1, w2, g64);
    k_h2    <<<N, 256, 0, stream>>>(g64, xo, cols, cnt, H2);
    k_score <<<N, 256, 0, stream>>>(H2, Mb, cols, cnt, coff, csr, as2, ad2, b2, score);
    k_rank  <<<N, 256, 0, stream>>>(score, cols, cnt, out);
}

// Round 4
// 406.973 us; speedup vs baseline: 2.8839x; 1.0228x over previous
//
#include <hip/hip_runtime.h>
#include <math.h>

#define N 1536
#define E 24576
#define HD 128
#define D 1280
#define NW 24   // 1536/64 bitmask words per row
#define RT 16   // rows per block in k_h
#define NCH 4   // j-chunks in k_h2 (384 cols/chunk -> 1.9MB, fits XCD L2)
#define CHW 384 // chunk width

typedef unsigned long long u64;
typedef unsigned short u16;

__device__ __forceinline__ double lrelu(double v){ return v > 0.0 ? v : 0.2*v; }

__device__ __forceinline__ int lbound(const u16* __restrict__ a, int n, int v){
    int lo = 0;
    while (lo < n){ int mid = (lo + n) >> 1; if (a[mid] < v) lo = mid + 1; else n = mid; }
    return lo;
}

// ---- IN bitmask (in-neighbors from the E raw edges) + in-degree incl. self-loop
__global__ void k_deg_in(const int* __restrict__ ei, u64* __restrict__ IN, int* __restrict__ deg){
    int idx = blockIdx.x*blockDim.x + threadIdx.x;
    if (idx < E){
        int s = ei[idx], t = ei[E+idx];
        atomicOr(&IN[(size_t)t*NW + (s>>6)], 1ULL << (s&63));
        atomicAdd(&deg[t], 1);
    } else if (idx < E+N){
        atomicAdd(&deg[idx-E], 1);
    }
}

// ---- exclusive scan of deg (1536 entries) -> coff[0..N], cursor copy
__global__ void k_scan(const int* __restrict__ deg, int* __restrict__ coff, int* __restrict__ cursor){
    __shared__ int ls[256];
    int tid = threadIdx.x;
    int v[6]; int s = 0;
    for (int u=0; u<6; u++){ v[u] = s; s += deg[tid*6+u]; }
    ls[tid] = s; __syncthreads();
    for (int d=1; d<256; d<<=1){
        int t2 = (tid>=d) ? ls[tid-d] : 0;
        __syncthreads();
        ls[tid] += t2;
        __syncthreads();
    }
    int base = (tid>0) ? ls[tid-1] : 0;
    for (int u=0; u<6; u++){
        int o = base + v[u];
        coff[tid*6+u] = o; cursor[tid*6+u] = o;
    }
    if (tid==255) coff[N] = ls[255];
}

// ---- fill CSR of in-edge sources (duplicates preserved; self-loops appended)
__global__ void k_fill(const int* __restrict__ ei, int* __restrict__ cursor, int* __restrict__ csr_src){
    int idx = blockIdx.x*blockDim.x + threadIdx.x;
    if (idx < E){
        int s = ei[idx], t = ei[E+idx];
        int p = atomicAdd(&cursor[t], 1);
        csr_src[p] = s;
    } else if (idx < E+N){
        int t = idx - E;
        int p = atomicAdd(&cursor[t], 1);
        csr_src[p] = t;
    }
}

// ---- 2-hop reachability row + column list. One wave per row.
__global__ void k_mrow(const u64* __restrict__ IN, u64* __restrict__ Mb,
                       u16* __restrict__ cols, int* __restrict__ cnt){
    int i = blockIdx.x, ln = threadIdx.x;   // blockDim = 64
    __shared__ u64 m1[NW];
    __shared__ int scn[64];
    u64 R = 0;
    if (ln < NW){
        u64 b = IN[(size_t)i*NW + ln];
        if ((i>>6) == ln) b |= 1ULL << (i&63);
        m1[ln] = b; R = b;
    }
    __syncthreads();
    for (int w=0; w<NW; w++){
        u64 bits = m1[w];                    // uniform across lanes
        while (bits){
            int k = __ffsll((unsigned long long)bits) - 1;
            bits &= bits - 1;
            int node = w*64 + k;
            if (ln < NW) R |= IN[(size_t)node*NW + ln];
        }
    }
    if (ln < NW) Mb[(size_t)i*NW + ln] = R;
    int pc = (ln < NW) ? __popcll(R) : 0;
    scn[ln] = pc; __syncthreads();
    for (int d=1; d<64; d<<=1){
        int v = (ln>=d) ? scn[ln-d] : 0;
        __syncthreads();
        scn[ln] += v;
        __syncthreads();
    }
    if (ln == 63) cnt[i] = scn[63];
    int idx = scn[ln] - pc;
    u64 bb = R;
    while (bb){
        int b = __ffsll((unsigned long long)bb) - 1;
        bb &= bb - 1;
        cols[(size_t)i*N + idx++] = (u16)(ln*64 + b);
    }
}

// ---- h = x @ W1 (f64). grid (D/256, N/RT). 16 rows/block: W1 reuse + 16 indep chains.
__global__ void k_h(const float* __restrict__ x, const float* __restrict__ W1, double* __restrict__ h64){
    int rb = blockIdx.y*RT, tid = threadIdx.x;
    int col = blockIdx.x*256 + tid;
    __shared__ double xL[RT*HD];   // 16 KB
    for (int u=tid; u<RT*HD; u+=256) xL[u] = (double)x[(size_t)rb*HD + u];
    __syncthreads();
    double acc[RT];
    #pragma unroll
    for (int r=0; r<RT; r++) acc[r] = 0.0;
    const float* wp = &W1[col];
    #pragma unroll 4
    for (int k=0; k<HD; k++){
        double w = (double)wp[(size_t)k*D];
        #pragma unroll
        for (int r=0; r<RT; r++) acc[r] += w * xL[r*HD + k];  // LDS broadcast
    }
    #pragma unroll
    for (int r=0; r<RT; r++) h64[(size_t)(rb+r)*D + col] = acc[r];
}

// ---- hs1 = h@a_src1, hd1 = h@a_dst1
__global__ void k_hv(const double* __restrict__ h64, const float* __restrict__ as1,
                     const float* __restrict__ ad1, double* __restrict__ hs1, double* __restrict__ hd1){
    int i = blockIdx.x, tid = threadIdx.x;
    __shared__ double ra[256], rb[256];
    double a = 0, b = 0;
    for (int d=tid; d<D; d+=256){
        double hv = h64[(size_t)i*D + d];
        a += hv * (double)as1[d];
        b += hv * (double)ad1[d];
    }
    ra[tid] = a; rb[tid] = b; __syncthreads();
    for (int s=128; s>0; s>>=1){
        if (tid < s){ ra[tid] += ra[tid+s]; rb[tid] += rb[tid+s]; }
        __syncthreads();
    }
    if (tid == 0){ hs1[i] = ra[0]; hd1[i] = rb[0]; }
}

// ---- stage-1 GAT gather per target: softmax over in-edges, g = (x_gat+b1)*w2
__global__ void k_gat(const int* __restrict__ coff, const int* __restrict__ csr_src,
                      const double* __restrict__ hs1, const double* __restrict__ hd1,
                      const double* __restrict__ h64,
                      const float* __restrict__ b1, const float* __restrict__ w2,
                      double* __restrict__ g64){
    int t = blockIdx.x, tid = threadIdx.x;
    int o0 = coff[t], o1 = coff[t+1], dg = o1 - o0;
    __shared__ double ms[256], ds[256], als[256];
    __shared__ int ssrc[256];
    __shared__ double MM, DD;
    double hdt = hd1[t];
    double m = -INFINITY, dsum = 0.0;
    for (int j=tid; j<dg; j+=256){
        int s = csr_src[o0+j];
        double e = lrelu(hs1[s] + hdt);
        if (e > m){ dsum = dsum*exp(m-e) + 1.0; m = e; }
        else dsum += exp(e-m);
    }
    ms[tid] = m; ds[tid] = dsum; __syncthreads();
    for (int step=128; step>0; step>>=1){
        if (tid < step){
            double m1 = ms[tid], d1 = ds[tid];
            double m2 = ms[tid+step], d2 = ds[tid+step];
            double M = fmax(m1, m2), Dv = 0.0;
            if (d1 > 0.0) Dv += d1*exp(m1-M);
            if (d2 > 0.0) Dv += d2*exp(m2-M);
            ms[tid] = M; ds[tid] = Dv;
        }
        __syncthreads();
    }
    if (tid == 0){ MM = ms[0]; DD = ds[0]; }
    __syncthreads();
    double M = MM, Dv = DD;
    double acc[5] = {0,0,0,0,0};
    for (int base=0; base<dg; base+=256){
        int j = base + tid;
        if (j < dg){
            int s = csr_src[o0+j];
            double e = lrelu(hs1[s] + hdt);
            als[tid] = exp(e-M)/Dv; ssrc[tid] = s;
        }
        __syncthreads();
        int lim = min(256, dg-base);
        for (int u=0; u<lim; u++){
            double a = als[u];
            const double* hp = &h64[(size_t)ssrc[u]*D];
            #pragma unroll
            for (int q=0; q<5; q++) acc[q] += a * hp[tid + 256*q];
        }
        __syncthreads();
    }
    #pragma unroll
    for (int q=0; q<5; q++){
        int d = tid + 256*q;
        g64[(size_t)t*D + d] = (acc[q] + (double)b1[d]) * (double)w2[d];
    }
}

// ---- sparse H2: j-chunked for XCD-L2 residency.
// Block b: chunk = b&3 (384 cols -> 1.9MB x-slice, L2-resident per XCD via %8
// round-robin dispatch); 4 waves = 4 consecutive rows, each wave owns its
// (row, chunk) range alone (g read once per row-chunk). Inner loop = proven
// 2-col / 10-loads-in-flight structure, g fragment in constant-indexed regs.
__global__ __launch_bounds__(256, 4)
void k_h2(const double* __restrict__ g64, const float* __restrict__ xo,
          const u16* __restrict__ cols, const int* __restrict__ cnt,
          double* __restrict__ H2){
    int b = blockIdx.x;
    int chunk = b & (NCH-1);
    int tid = threadIdx.x, wv = tid >> 6, ln = tid & 63;
    int i = ((b >> 2) << 2) + wv;
    double gr[5][4];
    #pragma unroll
    for (int k=0; k<5; k++){
        #pragma unroll
        for (int c=0; c<4; c++) gr[k][c] = g64[(size_t)i*D + ln*4 + 256*k + c];
    }
    int c0 = cnt[i];
    const u16* cp = &cols[(size_t)i*N];
    int v0 = chunk*CHW;
    int lo = lbound(cp, c0, v0);
    int hi = lbound(cp, c0, v0 + CHW);
    for (int cb = lo; cb < hi; cb += 2){
        int j0 = cp[cb];
        int j1 = cp[(cb+1 < hi) ? cb+1 : cb];
        const float4* p0 = (const float4*)(&xo[(size_t)j0*D]) + ln;
        const float4* p1 = (const float4*)(&xo[(size_t)j1*D]) + ln;
        double a0 = 0.0, a1 = 0.0;
        #pragma unroll
        for (int k=0; k<5; k++){
            float4 v0v = p0[64*k];
            float4 v1v = p1[64*k];
            a0 += gr[k][0]*(double)v0v.x + gr[k][1]*(double)v0v.y
                + gr[k][2]*(double)v0v.z + gr[k][3]*(double)v0v.w;
            a1 += gr[k][0]*(double)v1v.x + gr[k][1]*(double)v1v.y
                + gr[k][2]*(double)v1v.z + gr[k][3]*(double)v1v.w;
        }
        #pragma unroll
        for (int o=32; o>0; o>>=1){
            a0 += __shfl_down(a0, o, 64);
            a1 += __shfl_down(a1, o, 64);
        }
        if (ln == 0){
            H2[(size_t)i*N + j0] = a0;
            if (cb+1 < hi) H2[(size_t)i*N + j1] = a1;
        }
    }
}

// ---- stage-2 masked segment softmax score, gather per (row, target in Mb[i])
__global__ void k_score(const double* __restrict__ H2, const u64* __restrict__ Mb,
                        const u16* __restrict__ cols, const int* __restrict__ cnt,
                        const int* __restrict__ coff, const int* __restrict__ csr_src,
                        const float* __restrict__ pas2, const float* __restrict__ pad2,
                        const float* __restrict__ pb2, double* __restrict__ score){
    int i = blockIdx.x, tid = threadIdx.x;
    __shared__ double HL[N];
    __shared__ u64 MbL[NW];
    for (int d=tid; d<N; d+=256) HL[d] = H2[(size_t)i*N + d];
    if (tid < NW) MbL[tid] = Mb[(size_t)i*NW + tid];
    __syncthreads();
    double as2 = (double)pas2[0], ad2 = (double)pad2[0], b2 = (double)pb2[0];
    int c0 = cnt[i];
    for (int c=tid; c<c0; c+=256){
        int t = cols[(size_t)i*N + c];
        double ht = HL[t];
        int o0 = coff[t], o1 = coff[t+1];
        double m = -INFINITY, den = 0.0, nu = 0.0;
        for (int p=o0; p<o1; p++){
            int s = csr_src[p];
            if ((MbL[s>>6] >> (s&63)) & 1ULL){
                double hs = HL[s];
                double z = as2*hs + ad2*ht;
                double e = z > 0.0 ? z : 0.2*z;
                if (e > m){
                    double sc = exp(m-e);     // exp(-inf)=0 on first valid edge
                    den = den*sc + 1.0;
                    nu  = nu*sc + hs;
                    m = e;
                } else {
                    double w = exp(e-m);
                    den += w; nu += w*hs;
                }
            }
        }
        score[(size_t)i*N + t] = nu / fmax(den, 1e-12) + b2;
    }
}

// ---- per-row top-k selection (stable index tie-break) + outputs
__global__ void k_rank(const double* __restrict__ score, const u16* __restrict__ cols,
                       const int* __restrict__ cnt, float* __restrict__ out){
    int i = blockIdx.x, tid = threadIdx.x;
    __shared__ double scL[N];
    __shared__ u16 clL[N];
    int c0 = cnt[i];
    for (int c=tid; c<c0; c+=256){
        int t = cols[(size_t)i*N + c];
        clL[c] = (u16)t;
        scL[c] = score[(size_t)i*N + t];
    }
    __syncthreads();
    int k = (c0 + 1) >> 1;                 // ceil(0.5*size)
    float* keepO = out + (size_t)N*N;
    for (int p=tid; p<c0; p+=256){
        double s = scL[p]; int col = clL[p];
        int r = 0;
        for (int q=0; q<c0; q++){
            double sq = scL[q];
            r += (sq > s) || (sq == s && clL[q] < col);
        }
        if (r < k){
            out[(size_t)i*N + col]   = (float)(1.0/(1.0 + exp(-s)));
            keepO[(size_t)i*N + col] = 1.0f;
        }
    }
}

extern "C" void kernel_launch(void* const* d_in, const int* in_sizes, int n_in,
                              void* d_out, int out_size, void* d_ws, size_t ws_size,
                              hipStream_t stream){
    const float* x   = (const float*)d_in[0];
    const float* xo  = (const float*)d_in[1];
    const int*   ei  = (const int*)  d_in[2];
    // d_in[3] = batch (unused)
    const float* W1  = (const float*)d_in[4];
    const float* as1 = (const float*)d_in[5];
    const float* ad1 = (const float*)d_in[6];
    const float* b1  = (const float*)d_in[7];
    const float* w2  = (const float*)d_in[8];
    const float* as2 = (const float*)d_in[9];
    const float* ad2 = (const float*)d_in[10];
    const float* b2  = (const float*)d_in[11];
    float* out = (float*)d_out;

    char* w = (char*)d_ws;
    size_t o = 0;
    auto alloc = [&](size_t b)->char*{ char* r = w + o; o = (o + b + 255) & ~(size_t)255; return r; };

    double* h64   = (double*)alloc((size_t)N*D*8);   // dead after k_gat
    double* g64   = (double*)alloc((size_t)N*D*8);   // dead after k_h2
    double* H2    = (double*)alloc((size_t)N*N*8);
    u64*    IN    = (u64*)   alloc((size_t)N*NW*8);
    u64*    Mb    = (u64*)   alloc((size_t)N*NW*8);
    double* hs1   = (double*)alloc((size_t)N*8);
    double* hd1   = (double*)alloc((size_t)N*8);
    int*    deg   = (int*)   alloc((size_t)N*4);
    int*    coff  = (int*)   alloc((size_t)(N+1)*4);
    int*    cursor= (int*)   alloc((size_t)N*4);
    int*    csr   = (int*)   alloc((size_t)(E+N)*4);
    u16*    cols  = (u16*)   alloc((size_t)N*N*2);
    int*    cnt   = (int*)   alloc((size_t)N*4);
    // score overlays h64+g64 (both dead by the time k_score runs): 18.9MB <= 31.4MB
    double* score = (double*)h64;

    hipMemsetAsync(IN,  0, (size_t)N*NW*8, stream);
    hipMemsetAsync(deg, 0, (size_t)N*4,    stream);
    hipMemsetAsync(d_out, 0, (size_t)out_size*sizeof(float), stream);

    k_deg_in<<<(E+N+255)/256, 256, 0, stream>>>(ei, IN, deg);
    k_scan  <<<1, 256, 0, stream>>>(deg, coff, cursor);
    k_fill  <<<(E+N+255)/256, 256, 0, stream>>>(ei, cursor, csr);
    k_mrow  <<<N, 64, 0, stream>>>(IN, Mb, cols, cnt);
    k_h     <<<dim3(D/256, N/RT), 256, 0, stream>>>(x, W1, h64);
    k_hv    <<<N, 256, 0, stream>>>(h64, as1, ad1, hs1, hd1);
    k_gat   <<<N, 256, 0, stream>>>(coff, csr, hs1, hd1, h64, b1, w2, g64);
    k_h2    <<<N, 256, 0, stream>>>(g64, xo, cols, cnt, H2);   // N blocks = (N/4 rows) x 4 chunks
    k_score <<<N, 256, 0, stream>>>(H2, Mb, cols, cnt, coff, csr, as2, ad2, b2, score);
    k_rank  <<<N, 256, 0, stream>>>(score, cols, cnt, out);
}